// Round 8
// baseline (429.413 us; speedup 1.0000x reference)
//
#include <hip/hip_runtime.h>

#define B_N 4096
#define M_N 3
#define D_N 256
#define LOG2E 1.44269504088896340736f
#define LN2   0.69314718055994530942f
#define C_OFF 64.0f

typedef __bf16 bf16x8 __attribute__((ext_vector_type(8)));
typedef float  f32x4  __attribute__((ext_vector_type(4)));

__device__ __forceinline__ unsigned short f2bf(float f) {
    unsigned int u = __float_as_uint(f);
    u += 0x7FFFu + ((u >> 16) & 1u);   // round-to-nearest-even
    return (unsigned short)(u >> 16);
}
__device__ __forceinline__ float bf2f(unsigned short h) {
    return __uint_as_float(((unsigned int)h) << 16);
}

// tokens [i][m][d] f32 -> tokb [m][i][d] bf16
__global__ void cvt_kernel(const float* __restrict__ in, unsigned short* __restrict__ out) {
    int idx = blockIdx.x * 256 + threadIdx.x;   // 786432 float4s
    float4 v = reinterpret_cast<const float4*>(in)[idx];
    int i   = idx / 192;            // 192 = M*D/4
    int rem = idx - i * 192;
    int m   = rem >> 6;
    int d4  = rem & 63;
    ushort4 o;
    o.x = f2bf(v.x); o.y = f2bf(v.y); o.z = f2bf(v.z); o.w = f2bf(v.w);
    reinterpret_cast<ushort4*>(out)[((size_t)m * B_N + i) * 64 + d4] = o;
}

// label histogram (32 classes) + count of valid samples
__global__ void hist_kernel(const int* __restrict__ labels, int* __restrict__ hist,
                            int* __restrict__ nvout) {
    __shared__ int h[32];
    int tid = threadIdx.x;
    if (tid < 32) h[tid] = 0;
    __syncthreads();
    for (int i = tid; i < B_N; i += 1024) atomicAdd(&h[labels[i]], 1);
    __syncthreads();
    if (tid < 32) hist[tid] = h[tid];
    if (tid == 0) {
        int nv = 0;
#pragma unroll
        for (int c = 0; c < 32; ++c) nv += (h[c] >= 2) ? h[c] : 0;
        nvout[0] = nv;
    }
}

// Per-label token sums (partial centroids): cpart[m][part][label][d],
// part covers 1024 rows. 12 blocks x 1024 threads.
__global__ void centroid_kernel(const unsigned short* __restrict__ tokb,
                                const int* __restrict__ labels,
                                float* __restrict__ cpart) {
    int m = blockIdx.x >> 2, part = blockIdx.x & 3;
    int tid = threadIdx.x;
    __shared__ float Cl[32 * 256];
#pragma unroll
    for (int q = 0; q < 8; ++q) Cl[q * 1024 + tid] = 0.f;
    __syncthreads();
    int sub = tid >> 8, d = tid & 255;
    const unsigned short* tmm = tokb + (size_t)m * (B_N * D_N);
    int rbase = part * 1024;
    for (int it = 0; it < 256; ++it) {
        int row = rbase + it * 4 + sub;
        int lab = labels[row];
        atomicAdd(&Cl[lab * 256 + d], bf2f(tmm[(size_t)row * D_N + d]));
    }
    __syncthreads();
    float* dst = cpart + (size_t)(m * 4 + part) * 8192;
#pragma unroll
    for (int q = 0; q < 8; ++q) dst[q * 1024 + tid] = Cl[q * 1024 + tid];
}

// Block: 256 rows x 256 cols of one modality; 8 waves x 32 rows; 512 threads.
// Per phase: 16-col x 256-d B tile (8 KB) in double-buffered LDS, staged
// global->reg->ds_write (one 16B chunk/thread) with the verified XOR swizzle.
// Epilogue is label-free (positives handled via centroids in reduce).
// grid = 3m x 16ns x 16rb = 768 blocks = 2 blocks/CU, 16 waves/CU.
__global__ __launch_bounds__(512, 4) void main_kernel(
    const unsigned short* __restrict__ tokb, float* __restrict__ partialsS) {
    int raw = blockIdx.x;
    int bid = (raw & 7) * 96 + (raw >> 3);   // bijective XCD swizzle (768 % 8 == 0)
    int m  = bid >> 8;
    int ns = (bid >> 4) & 15;
    int rb = bid & 15;
    int i0 = rb * 256;
    int cb = ns * 256;

    int tid  = threadIdx.x;
    int wave = tid >> 6, lane = tid & 63;
    int lr = lane & 15, lk = lane >> 4;
    const unsigned short* tm = tokb + (size_t)m * (B_N * D_N);

    __shared__ __align__(16) char ldsB[2][8192];

    // A fragments: rows r0 + rt*16 + lr, registers for whole kernel
    int r0 = i0 + wave * 32;
    bf16x8 afrag[2][8];
#pragma unroll
    for (int rt = 0; rt < 2; ++rt) {
        const unsigned short* rp = tm + (size_t)(r0 + rt * 16 + lr) * D_N + lk * 8;
#pragma unroll
        for (int kf = 0; kf < 8; ++kf)
            afrag[rt][kf] = *reinterpret_cast<const bf16x8*>(rp + kf * 32);
    }

    float S[2][4] = {{0.f, 0.f, 0.f, 0.f}, {0.f, 0.f, 0.f, 0.f}};

    // Staging map (formula verified rounds 4-7): thread (lc = tid>>5 in 0..15,
    // w = tid&31) loads source chunk sch = w ^ (lc&7) of col cb+lc, writes LDS
    // linearly at tid*16 => LDS[col][ch] = G[col][ch ^ (col&7)].
    // Read applies the same XOR: G[lr][(kf*4+lk) ^ (lr&7) ^ (lr&7)] = correct.
    int lc  = tid >> 5;
    int w   = tid & 31;
    int sch = w ^ (lc & 7);
    const unsigned short* sbase = tm + (size_t)(cb + lc) * D_N + sch * 8;

    // prologue: tile 0 -> buf0
    *reinterpret_cast<bf16x8*>(&ldsB[0][tid * 16]) = *reinterpret_cast<const bf16x8*>(sbase);

    for (int kb = 0; kb < 16; ++kb) {
        int cur = kb & 1;
        __syncthreads();   // buf[cur] staged; all prior reads of buf[cur^1] done

        // issue next-tile load at phase top; compute covers its latency (r4 pattern)
        const unsigned short* np = sbase + (size_t)((kb + 1) & 15) * (16 * D_N);
        bf16x8 nt = *reinterpret_cast<const bf16x8*>(np);

        const char* bp = ldsB[cur];
        int swz = (lr & 7) << 4;
        bf16x8 bfrag[8];
#pragma unroll
        for (int kf = 0; kf < 8; ++kf)
            bfrag[kf] = *reinterpret_cast<const bf16x8*>(
                bp + lr * 512 + (((kf * 4 + lk) << 4) ^ swz));

        f32x4 acc0 = {0.f, 0.f, 0.f, 0.f};
        f32x4 acc1 = {0.f, 0.f, 0.f, 0.f};
#pragma unroll
        for (int kf = 0; kf < 8; ++kf) {
            acc0 = __builtin_amdgcn_mfma_f32_16x16x32_bf16(afrag[0][kf], bfrag[kf], acc0, 0, 0, 0);
            acc1 = __builtin_amdgcn_mfma_f32_16x16x32_bf16(afrag[1][kf], bfrag[kf], acc1, 0, 0, 0);
        }

        int cg0 = cb + kb * 16;
        if ((cg0 < r0 + 32) && (cg0 + 16 > r0)) {
            int colg = cg0 + lr;
#pragma unroll
            for (int rt = 0; rt < 2; ++rt) {
                f32x4 aa = rt ? acc1 : acc0;
#pragma unroll
                for (int j = 0; j < 4; ++j) {
                    float e = __builtin_amdgcn_exp2f(fmaf(aa[j], LOG2E, -C_OFF));
                    int row = r0 + rt * 16 + lk * 4 + j;
                    S[rt][j] += (colg == row) ? 0.f : e;  // diag Inf discarded by select
                }
            }
        } else {
#pragma unroll
            for (int rt = 0; rt < 2; ++rt) {
                f32x4 aa = rt ? acc1 : acc0;
#pragma unroll
                for (int j = 0; j < 4; ++j)
                    S[rt][j] += __builtin_amdgcn_exp2f(fmaf(aa[j], LOG2E, -C_OFF));
            }
        }

        // write next tile to other buffer; barrier at loop top publishes it
        *reinterpret_cast<bf16x8*>(&ldsB[cur ^ 1][tid * 16]) = nt;
    }

    // sum across the 16 col-lanes (lanes sharing lk hold the same rows)
#pragma unroll
    for (int rt = 0; rt < 2; ++rt)
#pragma unroll
        for (int j = 0; j < 4; ++j) {
            float sv = S[rt][j];
#pragma unroll
            for (int msk = 1; msk < 16; msk <<= 1) sv += __shfl_xor(sv, msk);
            if (lr == 0) {
                int rl = wave * 32 + rt * 16 + lk * 4 + j;
                partialsS[(size_t)(((m * 16 + rb) * 16 + ns)) * 256 + rl] = sv;
            }
        }
}

// one wave per (i,m): dot with label centroid (gives positive-sum + norm2),
// merge 16 col-split S partials, finish the loss term.
__global__ void reduce_kernel(const float* __restrict__ partialsS,
                              const unsigned short* __restrict__ tokb,
                              const int* __restrict__ labels,
                              const float* __restrict__ cpart,
                              const int* __restrict__ hist,
                              float* __restrict__ blockpart) {
    int tid = threadIdx.x;
    int wave = tid >> 6, lane = tid & 63;
    int gw = blockIdx.x * 4 + wave;      // 0..12287
    int m = gw >> 12, i = gw & 4095;
    int lab = labels[i];

    const unsigned short* xp = tokb + ((size_t)m * B_N + i) * D_N + (lane << 2);
    ushort4 xu = *reinterpret_cast<const ushort4*>(xp);
    float x0 = bf2f(xu.x), x1 = bf2f(xu.y), x2 = bf2f(xu.z), x3 = bf2f(xu.w);

    const float* cp = cpart + (size_t)m * 4 * 8192 + (size_t)lab * 256 + (lane << 2);
    float4 c = {0.f, 0.f, 0.f, 0.f};
#pragma unroll
    for (int p = 0; p < 4; ++p) {
        float4 cv = *reinterpret_cast<const float4*>(cp + p * 8192);
        c.x += cv.x; c.y += cv.y; c.z += cv.z; c.w += cv.w;
    }
    float dotC = x0 * c.x + x1 * c.y + x2 * c.z + x3 * c.w;
    float dotX = x0 * x0 + x1 * x1 + x2 * x2 + x3 * x3;
#pragma unroll
    for (int msk = 1; msk < 64; msk <<= 1) {
        dotC += __shfl_xor(dotC, msk);
        dotX += __shfl_xor(dotX, msk);
    }

    // 16 S-partials: lanes 0..15 load one each, 4-step reduce
    int rb = i >> 8, r = i & 255;
    const float* sp = partialsS + (size_t)((m * 16 + rb) * 16) * 256 + r;
    float Ssum = (lane < 16) ? sp[lane * 256] : 0.f;
#pragma unroll
    for (int msk = 1; msk < 16; msk <<= 1) Ssum += __shfl_xor(Ssum, msk);

    __shared__ float w4[4];
    if (lane == 0) {
        int pc = hist[lab] - 1;
        float contrib = (pc > 0)
            ? (__builtin_amdgcn_logf(Ssum) + C_OFF) * LN2 - (dotC - dotX) / (float)pc
            : 0.f;
        w4[wave] = contrib;
    }
    __syncthreads();
    if (tid == 0) blockpart[blockIdx.x] = w4[0] + w4[1] + w4[2] + w4[3];
}

__global__ void final_kernel(const float* __restrict__ blockpart, const int* __restrict__ nv,
                             float* __restrict__ out) {
    int tid = threadIdx.x;
    float s = 0.f;
    for (int i = tid; i < 3072; i += 1024) s += blockpart[i];
#pragma unroll
    for (int msk = 1; msk < 64; msk <<= 1) s += __shfl_xor(s, msk);
    __shared__ float wsum[16];
    if ((tid & 63) == 0) wsum[tid >> 6] = s;
    __syncthreads();
    if (tid == 0) {
        float t = 0.f;
#pragma unroll
        for (int q = 0; q < 16; ++q) t += wsum[q];
        out[0] = t / (float)(nv[0] * M_N);
    }
}

extern "C" void kernel_launch(void* const* d_in, const int* in_sizes, int n_in,
                              void* d_out, int out_size, void* d_ws, size_t ws_size,
                              hipStream_t stream) {
    const float* tokens = (const float*)d_in[0];
    const int*   labels = (const int*)d_in[1];
    float* out = (float*)d_out;

    char* ws = (char*)d_ws;
    int*   hist      = (int*)ws;                            // 32 ints @ 0
    int*   nv        = (int*)(ws + 128);                    // 1 int
    float* blockpart = (float*)(ws + 256);                  // 3072 f32, ends 12544
    float* partialsS = (float*)(ws + 16384);                // 786432 B, ends 802816
    float* cpart     = (float*)(ws + 802816);               // 393216 B, ends 1196032
    unsigned short* tokb = (unsigned short*)(ws + 1245184); // 6.29 MB, ends 7.19 MB

    cvt_kernel<<<3072, 256, 0, stream>>>(tokens, tokb);
    hist_kernel<<<1, 1024, 0, stream>>>(labels, hist, nv);
    centroid_kernel<<<12, 1024, 0, stream>>>(tokb, labels, cpart);
    main_kernel<<<768, 512, 0, stream>>>(tokb, partialsS);
    reduce_kernel<<<3072, 256, 0, stream>>>(partialsS, tokb, labels, cpart, hist, blockpart);
    final_kernel<<<1, 1024, 0, stream>>>(blockpart, nv, out);
}

// Round 9
// 394.899 us; speedup vs baseline: 1.0874x; 1.0874x over previous
//
#include <hip/hip_runtime.h>

#define B_N 4096
#define M_N 3
#define D_N 256
#define LOG2E 1.44269504088896340736f
#define LN2   0.69314718055994530942f
#define C_OFF 64.0f

typedef __bf16 bf16x8 __attribute__((ext_vector_type(8)));
typedef float  f32x4  __attribute__((ext_vector_type(4)));

__device__ __forceinline__ unsigned short f2bf(float f) {
    unsigned int u = __float_as_uint(f);
    u += 0x7FFFu + ((u >> 16) & 1u);   // round-to-nearest-even
    return (unsigned short)(u >> 16);
}

// tokens [i][m][d] f32 -> tokb [m][i][d] bf16
__global__ void cvt_kernel(const float* __restrict__ in, unsigned short* __restrict__ out) {
    int idx = blockIdx.x * 256 + threadIdx.x;   // 786432 float4s
    float4 v = reinterpret_cast<const float4*>(in)[idx];
    int i   = idx / 192;            // 192 = M*D/4
    int rem = idx - i * 192;
    int m   = rem >> 6;
    int d4  = rem & 63;
    ushort4 o;
    o.x = f2bf(v.x); o.y = f2bf(v.y); o.z = f2bf(v.z); o.w = f2bf(v.w);
    reinterpret_cast<ushort4*>(out)[((size_t)m * B_N + i) * 64 + d4] = o;
}

// Partial label centroids from f32 tokens. 12 blocks = 3m x 4 parts x 1024 rows.
// Thread d (=tid) owns column d EXCLUSIVELY -> no same-address collisions;
// atomicAdd with unused result emits no-return ds_add_f32 -> no dep chain.
__global__ __launch_bounds__(256) void cent1_kernel(const float* __restrict__ tokens,
                                                    const int* __restrict__ labels,
                                                    float* __restrict__ cpart) {
    int m = blockIdx.x >> 2, part = blockIdx.x & 3;
    int d = threadIdx.x;
    __shared__ float Cl[32 * 256];
    __shared__ int labl[1024];
#pragma unroll
    for (int q = 0; q < 32; ++q) Cl[q * 256 + d] = 0.f;
    int rbase = part * 1024;
#pragma unroll
    for (int q = 0; q < 4; ++q) labl[q * 256 + d] = labels[rbase + q * 256 + d];
    __syncthreads();
    const float* src = tokens + ((size_t)rbase * 3 + m) * 256 + d;
    for (int r = 0; r < 1024; r += 8) {
#pragma unroll
        for (int u = 0; u < 8; ++u) {
            float x = src[(size_t)(r + u) * 768];
            atomicAdd(&Cl[labl[r + u] * 256 + d], x);   // no-return ds_add_f32
        }
    }
    __syncthreads();
    float* dst = cpart + (size_t)(m * 4 + part) * 8192;
#pragma unroll
    for (int q = 0; q < 32; ++q) dst[q * 256 + d] = Cl[q * 256 + d];
}

// Merge 4 partial centroids -> centroid[m][lab][d]; block 0 also does hist+nv.
__global__ void cent2_kernel(const float* __restrict__ cpart, float* __restrict__ centroid,
                             const int* __restrict__ labels, int* __restrict__ hist,
                             int* __restrict__ nvout) {
    int g = blockIdx.x * 1024 + threadIdx.x;   // 24576 outputs
    int m = g >> 13, r = g & 8191;
    const float* cp = cpart + (size_t)m * 4 * 8192 + r;
    centroid[g] = cp[0] + cp[8192] + cp[16384] + cp[24576];
    if (blockIdx.x == 0) {
        __shared__ int h[32];
        int tid = threadIdx.x;
        if (tid < 32) h[tid] = 0;
        __syncthreads();
        for (int i = tid; i < B_N; i += 1024) atomicAdd(&h[labels[i]], 1);
        __syncthreads();
        if (tid < 32) hist[tid] = h[tid];
        if (tid == 0) {
            int nv = 0;
#pragma unroll
            for (int c = 0; c < 32; ++c) nv += (h[c] >= 2) ? h[c] : 0;
            nvout[0] = nv;
        }
    }
}

// Block: 256 rows x 256 cols of one modality; 4 waves x 64 rows (rt=4).
// Per phase: 16-col x 256-d B tile (8 KB) in double-buffered LDS, staged
// global->reg->ds_write with the round-4-verified XOR swizzle; label-free
// epilogue (positives via centroids). LDS reads per output HALVED vs round 4.
// grid = 3m x 16ns x 16rb = 768 blocks.
__global__ __launch_bounds__(256, 2) void main_kernel(
    const unsigned short* __restrict__ tokb, float* __restrict__ partialsS) {
    int raw = blockIdx.x;
    int bid = (raw & 7) * 96 + (raw >> 3);   // bijective XCD swizzle (768 % 8 == 0)
    int m  = bid >> 8;
    int ns = (bid >> 4) & 15;
    int rb = bid & 15;
    int i0 = rb * 256;
    int cb = ns * 256;

    int tid  = threadIdx.x;
    int wave = tid >> 6, lane = tid & 63;
    int lr = lane & 15, lk = lane >> 4;
    const unsigned short* tm = tokb + (size_t)m * (B_N * D_N);

    __shared__ __align__(16) char ldsB[2][8192];

    // A fragments: rows r0 + rt*16 + lr, registers for whole kernel
    int r0 = i0 + wave * 64;
    bf16x8 afrag[4][8];
#pragma unroll
    for (int rt = 0; rt < 4; ++rt) {
        const unsigned short* rp = tm + (size_t)(r0 + rt * 16 + lr) * D_N + lk * 8;
#pragma unroll
        for (int kf = 0; kf < 8; ++kf)
            afrag[rt][kf] = *reinterpret_cast<const bf16x8*>(rp + kf * 32);
    }

    float S[4][4];
#pragma unroll
    for (int rt = 0; rt < 4; ++rt)
#pragma unroll
        for (int j = 0; j < 4; ++j) S[rt][j] = 0.f;

    // Staging map (verified rounds 4-7): thread (lc = tid>>5, w = tid&31) loads
    // source chunk sch = w ^ (lc&7) of cols (cb+lc),(cb+lc+8); writes LDS
    // linearly at tid*16 / 4096+tid*16. Reads apply the same XOR.
    int lc  = tid >> 5;
    int w   = tid & 31;
    int sch = w ^ (lc & 7);
    const unsigned short* sbase = tm + (size_t)(cb + lc) * D_N + sch * 8;

    // prologue: tile 0 -> buf0
    {
        bf16x8 t0 = *reinterpret_cast<const bf16x8*>(sbase);
        bf16x8 t1 = *reinterpret_cast<const bf16x8*>(sbase + 8 * D_N);
        *reinterpret_cast<bf16x8*>(&ldsB[0][tid * 16])        = t0;
        *reinterpret_cast<bf16x8*>(&ldsB[0][4096 + tid * 16]) = t1;
    }

    for (int kb = 0; kb < 16; ++kb) {
        int cur = kb & 1;
        __syncthreads();   // buf[cur] staged; all prior reads of buf[cur^1] done

        // next-tile loads at phase top; compute covers their latency (r4 pattern)
        const unsigned short* np = sbase + (size_t)((kb + 1) & 15) * (16 * D_N);
        bf16x8 nt0 = *reinterpret_cast<const bf16x8*>(np);
        bf16x8 nt1 = *reinterpret_cast<const bf16x8*>(np + 8 * D_N);

        const char* bp = ldsB[cur];
        int swz = (lr & 7) << 4;
        bf16x8 bfrag[8];
#pragma unroll
        for (int kf = 0; kf < 8; ++kf)
            bfrag[kf] = *reinterpret_cast<const bf16x8*>(
                bp + lr * 512 + (((kf * 4 + lk) << 4) ^ swz));

        f32x4 acc[4];
#pragma unroll
        for (int rt = 0; rt < 4; ++rt) acc[rt] = f32x4{0.f, 0.f, 0.f, 0.f};
#pragma unroll
        for (int kf = 0; kf < 8; ++kf) {
#pragma unroll
            for (int rt = 0; rt < 4; ++rt)
                acc[rt] = __builtin_amdgcn_mfma_f32_16x16x32_bf16(
                    afrag[rt][kf], bfrag[kf], acc[rt], 0, 0, 0);
        }

        int cg0 = cb + kb * 16;
        if ((cg0 < r0 + 64) && (cg0 + 16 > r0)) {
            int colg = cg0 + lr;
#pragma unroll
            for (int rt = 0; rt < 4; ++rt) {
#pragma unroll
                for (int j = 0; j < 4; ++j) {
                    float e = __builtin_amdgcn_exp2f(fmaf(acc[rt][j], LOG2E, -C_OFF));
                    int row = r0 + rt * 16 + lk * 4 + j;
                    S[rt][j] += (colg == row) ? 0.f : e;  // diag Inf discarded by select
                }
            }
        } else {
#pragma unroll
            for (int rt = 0; rt < 4; ++rt) {
#pragma unroll
                for (int j = 0; j < 4; ++j)
                    S[rt][j] += __builtin_amdgcn_exp2f(fmaf(acc[rt][j], LOG2E, -C_OFF));
            }
        }

        // write next tile to other buffer; barrier at loop top publishes it
        *reinterpret_cast<bf16x8*>(&ldsB[cur ^ 1][tid * 16])        = nt0;
        *reinterpret_cast<bf16x8*>(&ldsB[cur ^ 1][4096 + tid * 16]) = nt1;
    }

    // sum across the 16 col-lanes (lanes sharing lk hold the same rows)
#pragma unroll
    for (int rt = 0; rt < 4; ++rt)
#pragma unroll
        for (int j = 0; j < 4; ++j) {
            float sv = S[rt][j];
#pragma unroll
            for (int msk = 1; msk < 16; msk <<= 1) sv += __shfl_xor(sv, msk);
            if (lr == 0) {
                int rl = wave * 64 + rt * 16 + lk * 4 + j;
                partialsS[(size_t)((m * 16 + rb) * 16 + ns) * 256 + rl] = sv;
            }
        }
}

// one wave per (i,m): P via centroid dot (exact f32), merge 16 S partials.
__global__ void reduce_kernel(const float* __restrict__ partialsS,
                              const float* __restrict__ tokens,
                              const int* __restrict__ labels,
                              const float* __restrict__ centroid,
                              const int* __restrict__ hist,
                              float* __restrict__ blockpart) {
    int tid = threadIdx.x;
    int wave = tid >> 6, lane = tid & 63;
    int gw = blockIdx.x * 4 + wave;      // 0..12287
    int m = gw >> 12, i = gw & 4095;
    int lab = labels[i];

    float4 x = *reinterpret_cast<const float4*>(tokens + ((size_t)i * 3 + m) * 256 + (lane << 2));
    float4 c = *reinterpret_cast<const float4*>(centroid + ((size_t)m * 32 + lab) * 256 + (lane << 2));
    float dotC = x.x * c.x + x.y * c.y + x.z * c.z + x.w * c.w;
    float dotX = x.x * x.x + x.y * x.y + x.z * x.z + x.w * x.w;
#pragma unroll
    for (int msk = 1; msk < 64; msk <<= 1) {
        dotC += __shfl_xor(dotC, msk);
        dotX += __shfl_xor(dotX, msk);
    }

    int rb = i >> 8, r = i & 255;
    const float* sp = partialsS + (size_t)((m * 16 + rb) * 16) * 256 + r;
    float Ssum = (lane < 16) ? sp[lane * 256] : 0.f;
#pragma unroll
    for (int msk = 1; msk < 16; msk <<= 1) Ssum += __shfl_xor(Ssum, msk);

    __shared__ float w4[4];
    if (lane == 0) {
        int pc = hist[lab] - 1;
        float contrib = (pc > 0)
            ? (__builtin_amdgcn_logf(Ssum) + C_OFF) * LN2 - (dotC - dotX) / (float)pc
            : 0.f;
        w4[wave] = contrib;
    }
    __syncthreads();
    if (tid == 0) blockpart[blockIdx.x] = w4[0] + w4[1] + w4[2] + w4[3];
}

__global__ void final_kernel(const float* __restrict__ blockpart, const int* __restrict__ nv,
                             float* __restrict__ out) {
    int tid = threadIdx.x;
    float s = 0.f;
    for (int i = tid; i < 3072; i += 1024) s += blockpart[i];
#pragma unroll
    for (int msk = 1; msk < 64; msk <<= 1) s += __shfl_xor(s, msk);
    __shared__ float wsum[16];
    if ((tid & 63) == 0) wsum[tid >> 6] = s;
    __syncthreads();
    if (tid == 0) {
        float t = 0.f;
#pragma unroll
        for (int q = 0; q < 16; ++q) t += wsum[q];
        out[0] = t / (float)(nv[0] * M_N);
    }
}

extern "C" void kernel_launch(void* const* d_in, const int* in_sizes, int n_in,
                              void* d_out, int out_size, void* d_ws, size_t ws_size,
                              hipStream_t stream) {
    const float* tokens = (const float*)d_in[0];
    const int*   labels = (const int*)d_in[1];
    float* out = (float*)d_out;

    char* ws = (char*)d_ws;
    int*   hist      = (int*)ws;                            // 32 ints @ 0
    int*   nv        = (int*)(ws + 128);                    // 1 int
    float* blockpart = (float*)(ws + 256);                  // 3072 f32, ends 12544
    // Region X @16384 (786 KB), stream-ordered overlay:
    //   cpart (393216 B): written by cent1, read by cent2 (before main)
    //   partialsS (786432 B): written by main, read by reduce
    float* cpart     = (float*)(ws + 16384);
    float* partialsS = (float*)(ws + 16384);
    float* centroid  = (float*)(ws + 802816);               // 98304 B, ends 901120
    unsigned short* tokb = (unsigned short*)(ws + 901120);  // 6.29 MB, ends 7.19 MB

    cvt_kernel<<<3072, 256, 0, stream>>>(tokens, tokb);
    cent1_kernel<<<12, 256, 0, stream>>>(tokens, labels, cpart);
    cent2_kernel<<<24, 1024, 0, stream>>>(cpart, centroid, labels, hist, nv);
    main_kernel<<<768, 256, 0, stream>>>(tokb, partialsS);
    reduce_kernel<<<3072, 256, 0, stream>>>(partialsS, tokens, labels, centroid, hist, blockpart);
    final_kernel<<<1, 1024, 0, stream>>>(blockpart, nv, out);
}

// Round 10
// 71.628 us; speedup vs baseline: 5.9950x; 5.5132x over previous
//
#include <hip/hip_runtime.h>

#define B_N 4096
#define M_N 3
#define D_N 256
#define LOG2E 1.44269504088896340736f
#define LN2   0.69314718055994530942f
#define C_OFF 64.0f

typedef __bf16 bf16x8 __attribute__((ext_vector_type(8)));
typedef float  f32x4  __attribute__((ext_vector_type(4)));

__device__ __forceinline__ unsigned short f2bf(float f) {
    unsigned int u = __float_as_uint(f);
    u += 0x7FFFu + ((u >> 16) & 1u);   // round-to-nearest-even
    return (unsigned short)(u >> 16);
}
__device__ __forceinline__ float bf2f(unsigned short h) {
    return __uint_as_float(((unsigned int)h) << 16);
}

// tokens [i][m][d] f32 -> tokb [m][i][d] bf16
__global__ void cvt_kernel(const float* __restrict__ in, unsigned short* __restrict__ out) {
    int idx = blockIdx.x * 256 + threadIdx.x;   // 786432 float4s
    float4 v = reinterpret_cast<const float4*>(in)[idx];
    int i   = idx / 192;            // 192 = M*D/4
    int rem = idx - i * 192;
    int m   = rem >> 6;
    int d4  = rem & 63;
    ushort4 o;
    o.x = f2bf(v.x); o.y = f2bf(v.y); o.z = f2bf(v.z); o.w = f2bf(v.w);
    reinterpret_cast<ushort4*>(out)[((size_t)m * B_N + i) * 64 + d4] = o;
}

// Partial label centroids. 48 blocks = 3m x 16 parts x 256 rows.
// Thread d owns column d exclusively -> plain LDS RMW (NO atomics, no fence):
// global loads pipeline freely; 16 register-staged loads per batch so each
// latency wait covers 16 rows.
__global__ __launch_bounds__(256) void cent1_kernel(const float* __restrict__ tokens,
                                                    const int* __restrict__ labels,
                                                    unsigned short* __restrict__ cpart) {
    int m = blockIdx.x >> 4, part = blockIdx.x & 15;
    int d = threadIdx.x;
    __shared__ float Cl[32 * 256];
    __shared__ int labl[256];
#pragma unroll
    for (int q = 0; q < 32; ++q) Cl[q * 256 + d] = 0.f;
    int rbase = part * 256;
    labl[d] = labels[rbase + d];
    __syncthreads();
    const float* src = tokens + ((size_t)rbase * 3 + m) * 256 + d;
    for (int r = 0; r < 256; r += 16) {
        float xv[16];
#pragma unroll
        for (int u = 0; u < 16; ++u) xv[u] = src[(size_t)(r + u) * 768];
#pragma unroll
        for (int u = 0; u < 16; ++u) Cl[labl[r + u] * 256 + d] += xv[u];  // exclusive: no race
    }
    __syncthreads();
    unsigned short* dst = cpart + (size_t)(m * 16 + part) * 8192;
#pragma unroll
    for (int q = 0; q < 32; ++q) dst[q * 256 + d] = f2bf(Cl[q * 256 + d]);
}

// Merge 16 bf16 partial centroids -> f32 centroid[m][lab][d]; block 0: hist+nv.
__global__ void cent2_kernel(const unsigned short* __restrict__ cpart,
                             float* __restrict__ centroid,
                             const int* __restrict__ labels, int* __restrict__ hist,
                             int* __restrict__ nvout) {
    int g = blockIdx.x * 1024 + threadIdx.x;   // 24576 outputs
    int m = g >> 13, r = g & 8191;
    const unsigned short* cp = cpart + (size_t)m * 16 * 8192 + r;
    float s = 0.f;
#pragma unroll
    for (int p = 0; p < 16; ++p) s += bf2f(cp[p * 8192]);
    centroid[g] = s;
    if (blockIdx.x == 0) {
        __shared__ int h[32];
        int tid = threadIdx.x;
        if (tid < 32) h[tid] = 0;
        __syncthreads();
        for (int i = tid; i < B_N; i += 1024) atomicAdd(&h[labels[i]], 1);
        __syncthreads();
        if (tid < 32) hist[tid] = h[tid];
        if (tid == 0) {
            int nv = 0;
#pragma unroll
            for (int c = 0; c < 32; ++c) nv += (h[c] >= 2) ? h[c] : 0;
            nvout[0] = nv;
        }
    }
}

// Block: 256 rows x 256 cols of one modality; 4 waves x 64 rows (rt=4).
// Per phase: 16-col x 256-d B tile (8 KB) in double-buffered LDS, staged
// global->reg->ds_write with the round-4-verified XOR swizzle; label-free
// epilogue (positives via centroids). grid = 3m x 16ns x 16rb = 768 blocks.
__global__ __launch_bounds__(256, 2) void main_kernel(
    const unsigned short* __restrict__ tokb, float* __restrict__ partialsS) {
    int raw = blockIdx.x;
    int bid = (raw & 7) * 96 + (raw >> 3);   // bijective XCD swizzle (768 % 8 == 0)
    int m  = bid >> 8;
    int ns = (bid >> 4) & 15;
    int rb = bid & 15;
    int i0 = rb * 256;
    int cb = ns * 256;

    int tid  = threadIdx.x;
    int wave = tid >> 6, lane = tid & 63;
    int lr = lane & 15, lk = lane >> 4;
    const unsigned short* tm = tokb + (size_t)m * (B_N * D_N);

    __shared__ __align__(16) char ldsB[2][8192];

    // A fragments: rows r0 + rt*16 + lr, registers for whole kernel
    int r0 = i0 + wave * 64;
    bf16x8 afrag[4][8];
#pragma unroll
    for (int rt = 0; rt < 4; ++rt) {
        const unsigned short* rp = tm + (size_t)(r0 + rt * 16 + lr) * D_N + lk * 8;
#pragma unroll
        for (int kf = 0; kf < 8; ++kf)
            afrag[rt][kf] = *reinterpret_cast<const bf16x8*>(rp + kf * 32);
    }

    float S[4][4];
#pragma unroll
    for (int rt = 0; rt < 4; ++rt)
#pragma unroll
        for (int j = 0; j < 4; ++j) S[rt][j] = 0.f;

    // Staging map (verified rounds 4-7): thread (lc = tid>>5, w = tid&31) loads
    // source chunk sch = w ^ (lc&7) of cols (cb+lc),(cb+lc+8); writes LDS
    // linearly at tid*16 / 4096+tid*16. Reads apply the same XOR.
    int lc  = tid >> 5;
    int w   = tid & 31;
    int sch = w ^ (lc & 7);
    const unsigned short* sbase = tm + (size_t)(cb + lc) * D_N + sch * 8;

    // prologue: tile 0 -> buf0
    {
        bf16x8 t0 = *reinterpret_cast<const bf16x8*>(sbase);
        bf16x8 t1 = *reinterpret_cast<const bf16x8*>(sbase + 8 * D_N);
        *reinterpret_cast<bf16x8*>(&ldsB[0][tid * 16])        = t0;
        *reinterpret_cast<bf16x8*>(&ldsB[0][4096 + tid * 16]) = t1;
    }

    for (int kb = 0; kb < 16; ++kb) {
        int cur = kb & 1;
        __syncthreads();   // buf[cur] staged; all prior reads of buf[cur^1] done

        // next-tile loads at phase top; compute covers their latency (r4 pattern)
        const unsigned short* np = sbase + (size_t)((kb + 1) & 15) * (16 * D_N);
        bf16x8 nt0 = *reinterpret_cast<const bf16x8*>(np);
        bf16x8 nt1 = *reinterpret_cast<const bf16x8*>(np + 8 * D_N);

        const char* bp = ldsB[cur];
        int swz = (lr & 7) << 4;
        bf16x8 bfrag[8];
#pragma unroll
        for (int kf = 0; kf < 8; ++kf)
            bfrag[kf] = *reinterpret_cast<const bf16x8*>(
                bp + lr * 512 + (((kf * 4 + lk) << 4) ^ swz));

        f32x4 acc[4];
#pragma unroll
        for (int rt = 0; rt < 4; ++rt) acc[rt] = f32x4{0.f, 0.f, 0.f, 0.f};
#pragma unroll
        for (int kf = 0; kf < 8; ++kf) {
#pragma unroll
            for (int rt = 0; rt < 4; ++rt)
                acc[rt] = __builtin_amdgcn_mfma_f32_16x16x32_bf16(
                    afrag[rt][kf], bfrag[kf], acc[rt], 0, 0, 0);
        }

        int cg0 = cb + kb * 16;
        if ((cg0 < r0 + 64) && (cg0 + 16 > r0)) {
            int colg = cg0 + lr;
#pragma unroll
            for (int rt = 0; rt < 4; ++rt) {
#pragma unroll
                for (int j = 0; j < 4; ++j) {
                    float e = __builtin_amdgcn_exp2f(fmaf(acc[rt][j], LOG2E, -C_OFF));
                    int row = r0 + rt * 16 + lk * 4 + j;
                    S[rt][j] += (colg == row) ? 0.f : e;  // diag Inf discarded by select
                }
            }
        } else {
#pragma unroll
            for (int rt = 0; rt < 4; ++rt) {
#pragma unroll
                for (int j = 0; j < 4; ++j)
                    S[rt][j] += __builtin_amdgcn_exp2f(fmaf(acc[rt][j], LOG2E, -C_OFF));
            }
        }

        // write next tile to other buffer; barrier at loop top publishes it
        *reinterpret_cast<bf16x8*>(&ldsB[cur ^ 1][tid * 16])        = nt0;
        *reinterpret_cast<bf16x8*>(&ldsB[cur ^ 1][4096 + tid * 16]) = nt1;
    }

    // sum across the 16 col-lanes (lanes sharing lk hold the same rows)
#pragma unroll
    for (int rt = 0; rt < 4; ++rt)
#pragma unroll
        for (int j = 0; j < 4; ++j) {
            float sv = S[rt][j];
#pragma unroll
            for (int msk = 1; msk < 16; msk <<= 1) sv += __shfl_xor(sv, msk);
            if (lr == 0) {
                int rl = wave * 64 + rt * 16 + lk * 4 + j;
                partialsS[(size_t)((m * 16 + rb) * 16 + ns) * 256 + rl] = sv;
            }
        }
}

// one wave per (i,m): P via centroid dot (exact f32), merge 16 S partials.
__global__ void reduce_kernel(const float* __restrict__ partialsS,
                              const float* __restrict__ tokens,
                              const int* __restrict__ labels,
                              const float* __restrict__ centroid,
                              const int* __restrict__ hist,
                              float* __restrict__ blockpart) {
    int tid = threadIdx.x;
    int wave = tid >> 6, lane = tid & 63;
    int gw = blockIdx.x * 4 + wave;      // 0..12287
    int m = gw >> 12, i = gw & 4095;
    int lab = labels[i];

    float4 x = *reinterpret_cast<const float4*>(tokens + ((size_t)i * 3 + m) * 256 + (lane << 2));
    float4 c = *reinterpret_cast<const float4*>(centroid + ((size_t)m * 32 + lab) * 256 + (lane << 2));
    float dotC = x.x * c.x + x.y * c.y + x.z * c.z + x.w * c.w;
    float dotX = x.x * x.x + x.y * x.y + x.z * x.z + x.w * x.w;
#pragma unroll
    for (int msk = 1; msk < 64; msk <<= 1) {
        dotC += __shfl_xor(dotC, msk);
        dotX += __shfl_xor(dotX, msk);
    }

    int rb = i >> 8, r = i & 255;
    const float* sp = partialsS + (size_t)((m * 16 + rb) * 16) * 256 + r;
    float Ssum = (lane < 16) ? sp[lane * 256] : 0.f;
#pragma unroll
    for (int msk = 1; msk < 16; msk <<= 1) Ssum += __shfl_xor(Ssum, msk);

    __shared__ float w4[4];
    if (lane == 0) {
        int pc = hist[lab] - 1;
        float contrib = (pc > 0)
            ? (__builtin_amdgcn_logf(Ssum) + C_OFF) * LN2 - (dotC - dotX) / (float)pc
            : 0.f;
        w4[wave] = contrib;
    }
    __syncthreads();
    if (tid == 0) blockpart[blockIdx.x] = w4[0] + w4[1] + w4[2] + w4[3];
}

__global__ void final_kernel(const float* __restrict__ blockpart, const int* __restrict__ nv,
                             float* __restrict__ out) {
    int tid = threadIdx.x;
    float s = 0.f;
    for (int i = tid; i < 3072; i += 1024) s += blockpart[i];
#pragma unroll
    for (int msk = 1; msk < 64; msk <<= 1) s += __shfl_xor(s, msk);
    __shared__ float wsum[16];
    if ((tid & 63) == 0) wsum[tid >> 6] = s;
    __syncthreads();
    if (tid == 0) {
        float t = 0.f;
#pragma unroll
        for (int q = 0; q < 16; ++q) t += wsum[q];
        out[0] = t / (float)(nv[0] * M_N);
    }
}

extern "C" void kernel_launch(void* const* d_in, const int* in_sizes, int n_in,
                              void* d_out, int out_size, void* d_ws, size_t ws_size,
                              hipStream_t stream) {
    const float* tokens = (const float*)d_in[0];
    const int*   labels = (const int*)d_in[1];
    float* out = (float*)d_out;

    char* ws = (char*)d_ws;
    int*   hist      = (int*)ws;                            // 32 ints @ 0
    int*   nv        = (int*)(ws + 128);                    // 1 int
    float* blockpart = (float*)(ws + 256);                  // 3072 f32, ends 12544
    // Region X @16384 (786432 B), stream-ordered overlay:
    //   cpart bf16 (3*16*8192*2 = 786432 B): cent1 writes, cent2 reads (pre-main)
    //   partialsS f32 (786432 B): main writes, reduce reads
    unsigned short* cpart = (unsigned short*)(ws + 16384);
    float* partialsS = (float*)(ws + 16384);
    float* centroid  = (float*)(ws + 802816);               // 98304 B, ends 901120
    unsigned short* tokb = (unsigned short*)(ws + 901120);  // 6.29 MB, ends 7.19 MB

    cvt_kernel<<<3072, 256, 0, stream>>>(tokens, tokb);
    cent1_kernel<<<48, 256, 0, stream>>>(tokens, labels, cpart);
    cent2_kernel<<<24, 1024, 0, stream>>>(cpart, centroid, labels, hist, nv);
    main_kernel<<<768, 256, 0, stream>>>(tokb, partialsS);
    reduce_kernel<<<3072, 256, 0, stream>>>(partialsS, tokens, labels, centroid, hist, blockpart);
    final_kernel<<<1, 1024, 0, stream>>>(blockpart, nv, out);
}